// Round 4
// baseline (129.532 us; speedup 1.0000x reference)
//
#include <hip/hip_runtime.h>
#include <hip/hip_bf16.h>

#define B 512
#define N 1024
#define D 1024
#define FUSE 1024
#define A 256

typedef float f32x4 __attribute__((ext_vector_type(4)));
typedef short bf16x8 __attribute__((ext_vector_type(8)));
typedef unsigned short u16x4 __attribute__((ext_vector_type(4)));

__device__ __forceinline__ float fast_exp2(float x) { return __builtin_amdgcn_exp2f(x); }
__device__ __forceinline__ float fast_rcp(float x)  { return __builtin_amdgcn_rcpf(x); }

static constexpr float TANH_C = 2.8853900817779268f; // 2*log2(e)
static constexpr float LOG2E  = 1.4426950408889634f;

__device__ __forceinline__ unsigned short f2bf(float x) {
    __hip_bfloat16 h = __float2bfloat16(x);
    return *reinterpret_cast<unsigned short*>(&h);
}

// ---------------------------------------------------------------------------
// Kernel 0: cast inputs to bf16. Straight: fuse_rep, conf. Transposed (so the
// GEMM B-operand is K-contiguous): conf^T, (Wq*TANH_C)^T, (Wk*TANH_C)^T.
// ---------------------------------------------------------------------------
__global__ __launch_bounds__(256) void cast_kernel(
    const float* __restrict__ fuse, const float* __restrict__ conf,
    const float* __restrict__ Wq, const float* __restrict__ Wk,
    short* __restrict__ fuse_bf, short* __restrict__ conf_bf,
    short* __restrict__ confT, short* __restrict__ WqT, short* __restrict__ WkT)
{
    __shared__ float tile[64 * 65];
    int bid = blockIdx.x;
    const float* src; short* dstS = nullptr; short* dstT = nullptr;
    int r0, c0, spitch; float scale = 1.0f;
    if (bid < 128) {                 // fuse straight: 8 x 16 tiles
        src = fuse; dstS = fuse_bf; spitch = FUSE;
        r0 = (bid >> 4) * 64; c0 = (bid & 15) * 64;
    } else if (bid < 384) {          // conf straight + transposed: 16 x 16
        int b = bid - 128; src = conf; dstS = conf_bf; dstT = confT; spitch = D;
        r0 = (b >> 4) * 64; c0 = (b & 15) * 64;
    } else if (bid < 448) {          // Wq transposed: src [1024][256], 16 x 4
        int b = bid - 384; src = Wq; dstT = WqT; spitch = A; scale = TANH_C;
        r0 = (b >> 2) * 64; c0 = (b & 3) * 64;
    } else {                         // Wk transposed
        int b = bid - 448; src = Wk; dstT = WkT; spitch = A; scale = TANH_C;
        r0 = (b >> 2) * 64; c0 = (b & 3) * 64;
    }
    const int tr = threadIdx.x >> 4, tc = (threadIdx.x & 15) * 4;

    f32x4 v[4];
#pragma unroll
    for (int i = 0; i < 4; ++i) {
        v[i] = *(const f32x4*)(src + (size_t)(r0 + tr + 16 * i) * spitch + c0 + tc);
#pragma unroll
        for (int j = 0; j < 4; ++j) v[i][j] *= scale;
    }
    if (dstS) {
#pragma unroll
        for (int i = 0; i < 4; ++i) {
            u16x4 o;
#pragma unroll
            for (int j = 0; j < 4; ++j) o[j] = f2bf(v[i][j]);
            *(u16x4*)(dstS + (size_t)(r0 + tr + 16 * i) * spitch + c0 + tc) = o;
        }
    }
    if (dstT) {
#pragma unroll
        for (int i = 0; i < 4; ++i)
#pragma unroll
            for (int j = 0; j < 4; ++j) tile[(tr + 16 * i) * 65 + tc + j] = v[i][j];
        __syncthreads();
#pragma unroll
        for (int i = 0; i < 4; ++i) {
            int orow = tr + 16 * i;          // column index in the source tile
            u16x4 o;
#pragma unroll
            for (int j = 0; j < 4; ++j) o[j] = f2bf(tile[(tc + j) * 65 + orow]);
            *(u16x4*)(dstT + (size_t)(c0 + orow) * 1024 + r0 + tc) = o;
        }
    }
}

// ---------------------------------------------------------------------------
// 64x64-tile bf16 MFMA GEMM, 2-phase double-buffered global_load_lds pipeline.
// C[M,N] f32 = A[M,K] bf16 x Bt[N,K]^T bf16 (both K-contiguous).
// LDS layout per tile: [64 rows][128 B], XOR-swizzled byte ^= ((row&7)<<4).
// global_load_lds writes linearly (lane*16B); the swizzle is applied by
// permuting the SOURCE address (m173 pattern), read applies the same XOR.
// ---------------------------------------------------------------------------
__device__ __forceinline__ void gemm64_pipe(
    const short* __restrict__ Ag, const short* __restrict__ Btg,
    float* __restrict__ C, int K, int ldc, int m0, int n0,
    char* As, char* Bs)   // 16384 bytes each: 2 buffers x 8192
{
    const int tid = threadIdx.x;
    const int w = tid >> 6, l = tid & 63;
    const int wm = w >> 1, wn = w & 1;
    const int lr = l & 15;              // frag row (A) / col (B)
    const int cr = (l >> 4) * 4;        // C frag row base
    const int rsub = l >> 3;            // row within 8-row chunk
    const int ssrc = ((l & 7) ^ rsub) << 3;  // pre-swizzled source offset, shorts

    auto stage = [&](int buf, int k0) {
#pragma unroll
        for (int p = 0; p < 2; ++p) {
            int chunk = (w << 1) | p;            // 0..7 (wave-uniform)
            int row = (chunk << 3) | rsub;       // 0..63
            int ldsoff = (buf << 13) | (chunk << 10);
            __builtin_amdgcn_global_load_lds(
                (const __attribute__((address_space(1))) unsigned int*)
                    (Ag + (size_t)(m0 + row) * K + k0 + ssrc),
                (__attribute__((address_space(3))) unsigned int*)(As + ldsoff),
                16, 0, 0);
            __builtin_amdgcn_global_load_lds(
                (const __attribute__((address_space(1))) unsigned int*)
                    (Btg + (size_t)(n0 + row) * K + k0 + ssrc),
                (__attribute__((address_space(3))) unsigned int*)(Bs + ldsoff),
                16, 0, 0);
        }
    };

    f32x4 acc[2][2] = {};
    const int nt = K >> 6;

    stage(0, 0);
    asm volatile("s_waitcnt vmcnt(0)" ::: "memory");
    __builtin_amdgcn_s_barrier();

    int cur = 0;
    for (int t = 0; t < nt; ++t) {
        if (t + 1 < nt) stage(cur ^ 1, (t + 1) << 6);

        const char* Ab = As + (cur << 13);
        const char* Bb = Bs + (cur << 13);
        bf16x8 af[2][2], bq[2][2];
#pragma unroll
        for (int ks = 0; ks < 2; ++ks)
#pragma unroll
            for (int i = 0; i < 2; ++i) {
                int j = ks * 64 + ((l >> 4) << 4);           // in-row byte
                int r = wm * 32 + i * 16 + lr;
                af[i][ks] = *(const bf16x8*)(Ab + r * 128 + (j ^ ((r & 7) << 4)));
                int c = wn * 32 + i * 16 + lr;
                bq[i][ks] = *(const bf16x8*)(Bb + c * 128 + (j ^ ((c & 7) << 4)));
            }
#pragma unroll
        for (int ks = 0; ks < 2; ++ks)
#pragma unroll
            for (int am = 0; am < 2; ++am)
#pragma unroll
                for (int bn = 0; bn < 2; ++bn)
                    acc[am][bn] = __builtin_amdgcn_mfma_f32_16x16x32_bf16(
                        af[am][ks], bq[bn][ks], acc[am][bn], 0, 0, 0);

        asm volatile("s_waitcnt vmcnt(0)" ::: "memory");
        __builtin_amdgcn_s_barrier();
        cur ^= 1;
    }

#pragma unroll
    for (int am = 0; am < 2; ++am)
#pragma unroll
        for (int bn = 0; bn < 2; ++bn) {
            float* cp = C + (size_t)(m0 + wm * 32 + am * 16 + cr) * ldc
                          + n0 + wn * 32 + bn * 16 + lr;
#pragma unroll
            for (int r = 0; r < 4; ++r) cp[(size_t)r * ldc] = acc[am][bn][r];
        }
}

// Kernel 1: q' = fuse_bf @ WqT^T, k' = conf_bf @ WkT^T (prescaled via W).
__global__ __launch_bounds__(256) void qk_gemm_kernel(
    const short* __restrict__ fuse_bf, const short* __restrict__ conf_bf,
    const short* __restrict__ WqT, const short* __restrict__ WkT,
    float* __restrict__ qbuf, float* __restrict__ kbuf)
{
    __shared__ char As[16384];
    __shared__ char Bs[16384];
    int bid = blockIdx.x;
    if (bid < 32) {       // q: M=512 -> 8 x 4 tiles
        gemm64_pipe(fuse_bf, WqT, qbuf, FUSE, A, (bid >> 2) * 64, (bid & 3) * 64, As, Bs);
    } else {              // k: M=1024 -> 16 x 4 tiles
        bid -= 32;
        gemm64_pipe(conf_bf, WkT, kbuf, D, A, (bid >> 2) * 64, (bid & 3) * 64, As, Bs);
    }
}

// Kernel 4: fin = w_bf @ confT^T
__global__ __launch_bounds__(256) void fin_gemm_kernel(
    const short* __restrict__ wb, const short* __restrict__ confT,
    float* __restrict__ out)
{
    __shared__ char As[16384];
    __shared__ char Bs[16384];
    gemm64_pipe(wb, confT, out, N, D, blockIdx.y * 64, blockIdx.x * 64, As, Bs);
}

// ---------------------------------------------------------------------------
// Kernel 2: s[b,n] = -2 * sum_a wt[a] * rcp(exp2(q'[b,a]+k'[n,a]) + 1)
// (softmax-shift-equivalent to sum_a wt[a]*tanh(q+k))
// ---------------------------------------------------------------------------
__global__ __launch_bounds__(256) void scores_kernel(
    const float* __restrict__ qbuf, const float* __restrict__ kbuf,
    const float* __restrict__ wt, float* __restrict__ s)
{
    __shared__ f32x4 qs[32 * 64];
    __shared__ f32x4 ks[32 * 64];
    const int tid = threadIdx.x;
    const int b0 = blockIdx.x * 32;
    const int n0 = blockIdx.y * 32;

    const f32x4* q4 = (const f32x4*)qbuf + (size_t)b0 * 64;
    const f32x4* k4 = (const f32x4*)kbuf + (size_t)n0 * 64;
#pragma unroll
    for (int j = 0; j < 8; ++j) {
        int idx = tid + j * 256;
        int r = idx >> 6, c = idx & 63;
        qs[idx] = q4[idx];
        ks[r * 64 + (c ^ (r & 15))] = k4[idx];
    }
    __syncthreads();

    const int bl = tid >> 5;   // 0..7
    const int nl = tid & 31;   // 0..31
    const f32x4* wt4 = (const f32x4*)wt;

    float acc0 = 0.f, acc1 = 0.f, acc2 = 0.f, acc3 = 0.f;
    for (int a4 = 0; a4 < 64; ++a4) {
        f32x4 kv = ks[nl * 64 + (a4 ^ (nl & 15))];
        f32x4 wv = wt4[a4];
        f32x4 q0 = qs[(bl) * 64 + a4];
        f32x4 q1 = qs[(bl + 8) * 64 + a4];
        f32x4 q2 = qs[(bl + 16) * 64 + a4];
        f32x4 q3 = qs[(bl + 24) * 64 + a4];
#pragma unroll
        for (int c = 0; c < 4; ++c) {
            float kc = kv[c], wc = wv[c];
            acc0 += wc * fast_rcp(fast_exp2(q0[c] + kc) + 1.0f);
            acc1 += wc * fast_rcp(fast_exp2(q1[c] + kc) + 1.0f);
            acc2 += wc * fast_rcp(fast_exp2(q2[c] + kc) + 1.0f);
            acc3 += wc * fast_rcp(fast_exp2(q3[c] + kc) + 1.0f);
        }
    }
    s[(size_t)(b0 + bl) * N + n0 + nl]      = -2.0f * acc0;
    s[(size_t)(b0 + bl + 8) * N + n0 + nl]  = -2.0f * acc1;
    s[(size_t)(b0 + bl + 16) * N + n0 + nl] = -2.0f * acc2;
    s[(size_t)(b0 + bl + 24) * N + n0 + nl] = -2.0f * acc3;
}

// ---------------------------------------------------------------------------
// Kernel 3: row softmax over N, times probs[n]; emit bf16 attn weights.
// ---------------------------------------------------------------------------
__global__ __launch_bounds__(256) void softmax_kernel(
    const float* __restrict__ s, const float* __restrict__ probs,
    short* __restrict__ wbuf)
{
    const int b = blockIdx.x, tid = threadIdx.x;
    const f32x4* s4 = (const f32x4*)(s + (size_t)b * N);
    f32x4 v = s4[tid];

    float m = fmaxf(fmaxf(v[0], v[1]), fmaxf(v[2], v[3]));
    for (int off = 32; off > 0; off >>= 1) m = fmaxf(m, __shfl_xor(m, off));
    __shared__ float redm[4];
    __shared__ float reds[4];
    const int wid = tid >> 6, lane = tid & 63;
    if (lane == 0) redm[wid] = m;
    __syncthreads();
    m = fmaxf(fmaxf(redm[0], redm[1]), fmaxf(redm[2], redm[3]));

    f32x4 e;
#pragma unroll
    for (int c = 0; c < 4; ++c) e[c] = fast_exp2((v[c] - m) * LOG2E);
    float sum = e[0] + e[1] + e[2] + e[3];
    for (int off = 32; off > 0; off >>= 1) sum += __shfl_xor(sum, off);
    if (lane == 0) reds[wid] = sum;
    __syncthreads();
    sum = reds[0] + reds[1] + reds[2] + reds[3];

    const float inv = fast_rcp(sum);
    const f32x4* p4 = (const f32x4*)probs;
    f32x4 p = p4[tid];
    u16x4 o;
#pragma unroll
    for (int c = 0; c < 4; ++c) o[c] = f2bf(e[c] * inv * p[c]);
    ((u16x4*)(wbuf + (size_t)b * N))[tid] = o;
}

// ---------------------------------------------------------------------------
extern "C" void kernel_launch(void* const* d_in, const int* in_sizes, int n_in,
                              void* d_out, int out_size, void* d_ws, size_t ws_size,
                              hipStream_t stream) {
    const float* conf     = (const float*)d_in[0]; // [N,D]
    const float* fuse_rep = (const float*)d_in[1]; // [B,FUSE]
    const float* probs    = (const float*)d_in[2]; // [1,N]
    const float* Wq       = (const float*)d_in[3]; // [FUSE,A]
    const float* Wk       = (const float*)d_in[4]; // [D,A]
    const float* wt       = (const float*)d_in[5]; // [A]
    float* out = (float*)d_out;                    // [B,D]

    char* w = (char*)d_ws;
    float* qbuf   = (float*)(w);                    //  512 KB  [0, 512K)
    float* kbuf   = (float*)(w + 524288);           //    1 MB  [512K, 1.5M)
    float* sbuf   = (float*)(w + 1572864);          //    2 MB  [1.5M, 3.5M)
    short* fuse_bf= (short*)(w + 3670016);          //    1 MB
    short* conf_bf= (short*)(w + 4718592);          //    2 MB
    short* confT  = (short*)(w + 6815744);          //    2 MB
    short* WqT    = (short*)(w + 8912896);          //  512 KB
    short* WkT    = (short*)(w + 9437184);          //  512 KB  (end ~9.5 MB)
    short* wbuf   = (short*)(w);                    // 1 MB, aliases qbuf/kbuf (free after scores)

    hipLaunchKernelGGL(cast_kernel, dim3(512), dim3(256), 0, stream,
                       fuse_rep, conf, Wq, Wk, fuse_bf, conf_bf, confT, WqT, WkT);
    hipLaunchKernelGGL(qk_gemm_kernel, dim3(96), dim3(256), 0, stream,
                       fuse_bf, conf_bf, WqT, WkT, qbuf, kbuf);
    hipLaunchKernelGGL(scores_kernel, dim3(B / 32, N / 32), dim3(256), 0, stream,
                       qbuf, kbuf, wt, sbuf);
    hipLaunchKernelGGL(softmax_kernel, dim3(B), dim3(256), 0, stream,
                       sbuf, probs, wbuf);
    hipLaunchKernelGGL(fin_gemm_kernel, dim3(D / 64, B / 64), dim3(256), 0, stream,
                       wbuf, confT, out);
}